// Round 14
// baseline (357.122 us; speedup 1.0000x reference)
//
#include <hip/hip_runtime.h>

typedef unsigned short u16;
typedef unsigned int u32;
typedef unsigned char u8;
typedef unsigned long long u64;

typedef __attribute__((ext_vector_type(8))) short bf16x8;
typedef __attribute__((ext_vector_type(4))) short bf16x4;
typedef __attribute__((ext_vector_type(4))) float f32x4;

__device__ __forceinline__ float bf2f(u16 u) {
    union { u32 i; float f; } v; v.i = ((u32)u) << 16; return v.f;
}
__device__ __forceinline__ u16 f2bf(float f) {
    union { float f; u32 i; } v; v.f = f;
    u32 r = v.i + 0x7fffu + ((v.i >> 16) & 1u);
    return (u16)(r >> 16);
}
// pack two f32 -> bf16x2 in one u32 (low = a, high = b). Software RNE,
// bit-identical to f2bf pair, packed with ONE v_perm_b32.
// (HW v_cvt_pk_bf16_f32 retired: rounds/packs differently -> r1/r8 failures.)
__device__ __forceinline__ u32 pkbf(float a, float b) {
    union { float f; u32 i; } va, vb;
    va.f = a; vb.f = b;
    u32 ra = va.i + 0x7fffu + ((va.i >> 16) & 1u);
    u32 rb = vb.i + 0x7fffu + ((vb.i >> 16) & 1u);
    return __builtin_amdgcn_perm(rb, ra, 0x07060302u);
}
// raw v_exp_f32 (2^x). <=2 ULP vs OCML exp2f — negligible for softmax P.
__device__ __forceinline__ float fexp2(float x) { return __builtin_amdgcn_exp2f(x); }

// async global->LDS, 16B per lane; lds must be wave-uniform (lane*16 added by HW)
__device__ __forceinline__ void async16(u16* lds, const u16* g) {
    __builtin_amdgcn_global_load_lds(
        (const __attribute__((address_space(1))) void*)g,
        (__attribute__((address_space(3))) void*)lds, 16, 0, 0);
}

// =============================================================== PREP
// One dispatch: [0..4096) LayerNorm rows, [4096..5120) weight transpose,
// block 5120 writes flag. (K/V f32->bf16 conversion fused into VK A-staging.)
// Every block self-detects dtype on x's first 4KB (identical words+threshold
// as the old detect_dtype kernel -> bit-identical decision; L2-broadcast).
__global__ __launch_bounds__(256) void prep_kernel(
        const u32* __restrict__ xw,          // x as words (for detect)
        const void* __restrict__ x_,
        const void* __restrict__ g_,
        const void* __restrict__ b_,
        const void* __restrict__ Wq, const void* __restrict__ Wk,
        const void* __restrict__ Wv, const void* __restrict__ Wo,
        u16* __restrict__ xn,
        u16* __restrict__ Wqt, u16* __restrict__ Wkt,
        u16* __restrict__ Wvt, u16* __restrict__ Wot,
        int* __restrict__ flagp) {
    __shared__ int  redi[4];
    __shared__ float redf[8];
    __shared__ u16 tsh[64][65];

    int tid = threadIdx.x;
    int wave = tid >> 6, lane = tid & 63;

    // --- self-detect on x[0..1023] words (matches old detect_dtype exactly)
    int hits = 0;
    for (int i = 0; i < 4; ++i) {
        u32 w = xw[tid * 4 + i];
        u32 e = (w >> 7) & 0xFFu;
        hits += (e >= 110u && e <= 131u) ? 1 : 0;
    }
    for (int off = 1; off < 64; off <<= 1) hits += __shfl_xor(hits, off, 64);
    if (lane == 0) redi[wave] = hits;
    __syncthreads();
    int flag = (redi[0] + redi[1] + redi[2] + redi[3] > 512) ? 1 : 0;

    int blk = blockIdx.x;

    if (blk == 5120) {                        // flag writer for later gemms
        if (tid == 0) flagp[0] = flag;
        return;
    }

    if (blk < 4096) {
        // ---------------- LayerNorm row
        int row = blk;
        float v[4];
        if (flag) {
            const u16* xr = (const u16*)x_ + (size_t)row * 1024;
            uint2 d = *(const uint2*)&xr[tid * 4];
            v[0] = bf2f((u16)(d.x & 0xffff));
            v[1] = bf2f((u16)(d.x >> 16));
            v[2] = bf2f((u16)(d.y & 0xffff));
            v[3] = bf2f((u16)(d.y >> 16));
        } else {
            const float* xr = (const float*)x_ + (size_t)row * 1024;
            float4 d = *(const float4*)&xr[tid * 4];
            v[0] = d.x; v[1] = d.y; v[2] = d.z; v[3] = d.w;
        }
        float s  = v[0] + v[1] + v[2] + v[3];
        float ss = v[0]*v[0] + v[1]*v[1] + v[2]*v[2] + v[3]*v[3];
        for (int off = 1; off < 64; off <<= 1) {
            s  += __shfl_xor(s,  off, 64);
            ss += __shfl_xor(ss, off, 64);
        }
        if (lane == 0) { redf[wave] = s; redf[4 + wave] = ss; }
        __syncthreads();
        s  = redf[0] + redf[1] + redf[2] + redf[3];
        ss = redf[4] + redf[5] + redf[6] + redf[7];
        float mu   = s * (1.0f / 1024.0f);
        float var  = ss * (1.0f / 1024.0f) - mu * mu;
        float rstd = rsqrtf(var + 1e-5f);
        float r[4];
        for (int j = 0; j < 4; ++j) {
            float g, bb;
            if (flag) { g = bf2f(((const u16*)g_)[tid * 4 + j]); bb = bf2f(((const u16*)b_)[tid * 4 + j]); }
            else      { g = ((const float*)g_)[tid * 4 + j];     bb = ((const float*)b_)[tid * 4 + j]; }
            r[j] = (v[j] - mu) * rstd * g + bb;
        }
        uint2 o;
        o.x = pkbf(r[0], r[1]);
        o.y = pkbf(r[2], r[3]);
        *(uint2*)&xn[(size_t)row * 1024 + tid * 4] = o;
    } else {
        // ---------------- weight transpose (64x64 tile)
        int t = blk - 4096;
        int w = t >> 8;                       // which weight
        int tt = t & 255;
        const void* src_ = (w == 0) ? Wq : (w == 1) ? Wk : (w == 2) ? Wv : Wo;
        u16* dst = (w == 0) ? Wqt : (w == 1) ? Wkt : (w == 2) ? Wvt : Wot;
        int bx = (tt & 15) * 64;
        int by = (tt >> 4) * 64;
        const int rows = 1024, cols = 1024;
        for (int i = 0; i < 16; ++i) {
            int r = i * 4 + (tid >> 6);
            int c = tid & 63;
            size_t idx = (size_t)(by + r) * cols + bx + c;
            tsh[r][c] = flag ? ((const u16*)src_)[idx] : f2bf(((const float*)src_)[idx]);
        }
        __syncthreads();
        for (int i = 0; i < 16; ++i) {
            int r = i * 4 + (tid >> 6);
            int c = tid & 63;
            dst[(size_t)(bx + r) * rows + by + c] = tsh[c][r];
        }
    }
}

// ================================= GEMM 64x128 tile body (M=4096 shapes)
__device__ __forceinline__ void gemm64_body(u16* As, u16* Bs,
                                            const u16* __restrict__ A,
                                            const u16* __restrict__ Bt,
                                            void* __restrict__ C_,
                                            int flag, int c_flagged, float cscale,
                                            int lid) {
    const int N = 1024, K = 1024, mdiv = 8;   // M = 4096 -> 64 m-tiles
    bool c_bf16 = c_flagged ? (flag != 0) : true;

    int j   = lid >> 3;
    int gy  = (lid & 7) + 8 * (j % mdiv);
    int bnt = j / mdiv;

    int tid  = threadIdx.x;
    int wave = tid >> 6, lane = tid & 63;
    int quad = lane >> 4, l16 = lane & 15;
    size_t bm = (size_t)gy * 64;
    size_t bn = (size_t)bnt * 128;
    int wm = (wave >> 1) * 32, wn = (wave & 1) * 64;

    int lr  = lane >> 3;
    int csw = (lane & 7) ^ lr;
    const u16* Ag = A  + (bm + wave * 8 + lr) * (size_t)K + csw * 8;
    const u16* Bg = Bt + (bn + wave * 8 + lr) * (size_t)K + csw * 8;
    u16* Al = &As[(wave * 8) * 64];
    u16* Bl = &Bs[(wave * 8) * 64];

    f32x4 acc[2][4];
#pragma unroll
    for (int i = 0; i < 2; ++i)
#pragma unroll
        for (int jj = 0; jj < 4; ++jj)
            acc[i][jj] = (f32x4){0.f, 0.f, 0.f, 0.f};

    int rsw = l16 & 7;

    for (int k0 = 0; k0 < K; k0 += 64) {
        __syncthreads();
#pragma unroll
        for (int i = 0; i < 2; ++i)
            async16(Al + i * 32 * 64, Ag + (size_t)i * 32 * K + k0);
#pragma unroll
        for (int i = 0; i < 4; ++i)
            async16(Bl + i * 32 * 64, Bg + (size_t)i * 32 * K + k0);
        __syncthreads();

#pragma unroll
        for (int ks = 0; ks < 2; ++ks) {
            int chunk = ((ks << 2) | quad) ^ rsw;
            bf16x8 af[2], bfr[4];
#pragma unroll
            for (int mi = 0; mi < 2; ++mi)
                af[mi]  = *(const bf16x8*)&As[(wm + mi * 16 + l16) * 64 + chunk * 8];
#pragma unroll
            for (int ni = 0; ni < 4; ++ni)
                bfr[ni] = *(const bf16x8*)&Bs[(wn + ni * 16 + l16) * 64 + chunk * 8];
#pragma unroll
            for (int mi = 0; mi < 2; ++mi)
#pragma unroll
                for (int ni = 0; ni < 4; ++ni)
                    acc[mi][ni] = __builtin_amdgcn_mfma_f32_16x16x32_bf16(
                        af[mi], bfr[ni], acc[mi][ni], 0, 0, 0);
        }
    }

#pragma unroll
    for (int mi = 0; mi < 2; ++mi)
#pragma unroll
        for (int ni = 0; ni < 4; ++ni)
#pragma unroll
            for (int r = 0; r < 4; ++r) {
                size_t row = bm + wm + mi * 16 + quad * 4 + r;
                size_t col = bn + wn + ni * 16 + l16;
                float val = acc[mi][ni][r] * cscale;
                if (c_bf16) ((u16*)C_)[row * N + col]   = f2bf(val);
                else        ((float*)C_)[row * N + col] = val;
            }
}

// ========================= MID: V-GEMM + K-GEMM + Q-GEMM + mask_bits merged
// Round 13: segment ORDER = VK first (critical path starts immediately),
// then Q, then mask; launch_bounds (256,5) -> 5 blocks/CU (LDS-capped max;
// VGPR budget 512/5=102 >= measured 76, no spill expected).
// [0..1024): VK gemm (seg 0=V, 1=K, fused f32->bf16 A-staging).
// [1024..1536): Q-gemm (64-tile).  [1536..2560): mask -> bit pack.
__global__ __launch_bounds__(256, 5) void mid_kernel(
        const void* __restrict__ A0, const u16* __restrict__ Bt0, u16* __restrict__ C0,
        const void* __restrict__ A1, const u16* __restrict__ Bt1, u16* __restrict__ C1,
        const u16* __restrict__ Aq, const u16* __restrict__ Btq, u16* __restrict__ Cq,
        float cscale,
        const int* __restrict__ m, u64* __restrict__ mb,
        const int* __restrict__ flagp) {
    __shared__ u16 sh[2 * 128 * 64];
    int blk = blockIdx.x;
    int tid = threadIdx.x;

    if (blk >= 1024 && blk < 1536) {
        // ---------------- Q projection gemm (xn x Wqt -> q, scaled)
        gemm64_body(sh, &sh[64 * 64], Aq, Btq, (void*)Cq, 1, 0, cscale, blk - 1024);
        return;
    }
    if (blk >= 1536) {
        // ---------------- mask bits (bit kv == __ballot lane)
        int mblk = blk - 1536;
        int wid  = (mblk * 256 + tid) >> 6;
        int lane = tid & 63;
        size_t base = (size_t)wid * 2048;
        for (int it = 0; it < 8; ++it) {
            u64 b0 = __ballot(m[base + it * 256 +   0 + lane] == 0);
            u64 b1 = __ballot(m[base + it * 256 +  64 + lane] == 0);
            u64 b2 = __ballot(m[base + it * 256 + 128 + lane] == 0);
            u64 b3 = __ballot(m[base + it * 256 + 192 + lane] == 0);
            if (lane == 0) {
                size_t idx = (base + it * 256) >> 6;
                mb[idx + 0] = b0; mb[idx + 1] = b1; mb[idx + 2] = b2; mb[idx + 3] = b3;
            }
        }
        return;
    }

    // ---------------- VK gemm (128-tile), fused f32->bf16 A-staging
    u16* As = sh;
    u16* Bs = &sh[128 * 64];
    const int N = 1024, K = 1024, mdiv = 8;
    int flag = *flagp;

    int id  = blk;
    int seg = id >> 9;                 // 0 = V, 1 = K
    int lid = id & 511;
    const void* A  = seg ? A1 : A0;
    const u16* Bt = seg ? Bt1 : Bt0;

    int j   = lid >> 3;
    int gy  = (lid & 7) + 8 * (j % mdiv);
    int bnt = j / mdiv;

    int wave = tid >> 6, lane = tid & 63;
    int quad = lane >> 4, l16 = lane & 15;
    size_t bm = (size_t)gy * 128;
    size_t bn = (size_t)bnt * 128;
    int wm = (wave >> 1) * 64, wn = (wave & 1) * 64;

    int lr  = lane >> 3;
    int csw = (lane & 7) ^ lr;
    size_t arow = bm + wave * 32 + lr;
    int    acol = csw * 8;
    const u16* Bg = Bt + (bn + wave * 32 + lr) * (size_t)K + acol;
    u16* Al = &As[(wave * 32) * 64];
    u16* Bl = &Bs[(wave * 32) * 64];

    f32x4 acc[4][4];
#pragma unroll
    for (int i = 0; i < 4; ++i)
#pragma unroll
        for (int jj = 0; jj < 4; ++jj)
            acc[i][jj] = (f32x4){0.f, 0.f, 0.f, 0.f};

    int rsw = l16 & 7;

    for (int k0 = 0; k0 < K; k0 += 64) {
        __syncthreads();
        // B: async global->LDS (proven path)
#pragma unroll
        for (int i = 0; i < 4; ++i)
            async16(Bl + i * 8 * 64, Bg + (size_t)i * 8 * K + k0);
        // A: reg-staged with fused dtype conversion; identical LDS layout
        if (flag) {
#pragma unroll
            for (int i = 0; i < 4; ++i) {
                size_t gidx = (arow + i * 8) * (size_t)K + k0 + acol;
                uint4 v = *(const uint4*)&((const u16*)A)[gidx];
                *(uint4*)&Al[i * 8 * 64 + lane * 8] = v;
            }
        } else {
#pragma unroll
            for (int i = 0; i < 4; ++i) {
                size_t gidx = (arow + i * 8) * (size_t)K + k0 + acol;
                float4 f0 = *(const float4*)&((const float*)A)[gidx];
                float4 f1 = *(const float4*)&((const float*)A)[gidx + 4];
                uint4 v;
                v.x = pkbf(f0.x, f0.y);
                v.y = pkbf(f0.z, f0.w);
                v.z = pkbf(f1.x, f1.y);
                v.w = pkbf(f1.z, f1.w);
                *(uint4*)&Al[i * 8 * 64 + lane * 8] = v;
            }
        }
        __syncthreads();

#pragma unroll
        for (int ks = 0; ks < 2; ++ks) {
            int chunk = ((ks << 2) | quad) ^ rsw;
            bf16x8 af[4], bfr[4];
#pragma unroll
            for (int mi = 0; mi < 4; ++mi)
                af[mi]  = *(const bf16x8*)&As[(wm + mi * 16 + l16) * 64 + chunk * 8];
#pragma unroll
            for (int ni = 0; ni < 4; ++ni)
                bfr[ni] = *(const bf16x8*)&Bs[(wn + ni * 16 + l16) * 64 + chunk * 8];
#pragma unroll
            for (int mi = 0; mi < 4; ++mi)
#pragma unroll
                for (int ni = 0; ni < 4; ++ni)
                    acc[mi][ni] = __builtin_amdgcn_mfma_f32_16x16x32_bf16(
                        af[mi], bfr[ni], acc[mi][ni], 0, 0, 0);
        }
    }

    if (!seg) {
        // V: transposed per-head layout [b][h][d][kv].
        // Stage acc into sh as [n=hd][m=kv] bf16 (XOR-swizzled 16B chunks),
        // then write rows back coalesced (256B segments).
        __syncthreads();
#pragma unroll
        for (int ni = 0; ni < 4; ++ni) {
            int n  = wn + ni * 16 + l16;
            int s7 = n & 7;
#pragma unroll
            for (int mi = 0; mi < 4; ++mi) {
                int mm = wm + mi * 16 + quad * 4;
                int base = n * 128 + ((((mm >> 3) ^ s7) << 3) | (mm & 7));
                *(u32*)&sh[base]     = pkbf(acc[mi][ni][0], acc[mi][ni][1]);
                *(u32*)&sh[base + 2] = pkbf(acc[mi][ni][2], acc[mi][ni][3]);
            }
        }
        __syncthreads();
        int trow = tid >> 4;
        int tch  = tid & 15;
        size_t bb = bm >> 11;
        size_t kvb = (bm & 2047) + tch * 8;
        u16* C = C0;
#pragma unroll
        for (int it = 0; it < 8; ++it) {
            int n = it * 16 + trow;
            uint4 v = *(const uint4*)&sh[n * 128 + ((tch ^ (n & 7)) << 3)];
            size_t ng = bn + n;
            size_t hh = ng >> 6, d = ng & 63;
            *(uint4*)&C[((bb * 16 + hh) * 64 + d) * 2048 + kvb] = v;
        }
    } else {
        u16* C = C1;
#pragma unroll
        for (int mi = 0; mi < 4; ++mi)
#pragma unroll
            for (int ni = 0; ni < 4; ++ni)
#pragma unroll
                for (int r = 0; r < 4; ++r) {
                    size_t row = bm + wm + mi * 16 + quad * 4 + r;
                    size_t col = bn + wn + ni * 16 + l16;
                    C[row * N + col] = f2bf(acc[mi][ni][r]);
                }
    }
}

// =============================================== O-GEMM (64-tile, flag out)
// (256,6): 6 blocks/CU (24KB LDS -> 144KB; VGPR cap 512/6=85 >= measured 76)
__global__ __launch_bounds__(256, 6) void ogemm64(const u16* __restrict__ A,
                                                  const u16* __restrict__ Bt,
                                                  void* __restrict__ C_,
                                                  const int* __restrict__ flagp) {
    __shared__ u16 As[64 * 64];
    __shared__ u16 Bs[128 * 64];
    int flag = *flagp;
    gemm64_body(As, Bs, A, Bt, C_, flag, 1, 1.0f, blockIdx.x);
}

// ---------------------------------------------------------------- Attention
// S^T formulation, XCD-grouped, async XOR-swizzled staging, 2-way KV-split.
// P-pack: software RNE pkbf (perm-packed, bit-exact). HW cvt_pk retired.
__global__ __launch_bounds__(256) void attn_kernel(const u16* __restrict__ qg,
                                                   const u16* __restrict__ kg,
                                                   const u16* __restrict__ vtg,
                                                   const u32* __restrict__ mbits,
                                                   float* __restrict__ o0b0,
                                                   float* __restrict__ o0b1,
                                                   float* __restrict__ o0b2,
                                                   float* __restrict__ o0b3,
                                                   float* __restrict__ o1b0,
                                                   float* __restrict__ o1b1,
                                                   float* __restrict__ o1b2,
                                                   float* __restrict__ o1b3,
                                                   float* __restrict__ lacc0,
                                                   float* __restrict__ lacc1) {
    __shared__ u16 Ks[64 * 64];
    __shared__ u16 Vst[64 * 64];     // [d][kv], swizzled

    const int NQc = 1024, NKVc = 2048, HD = 1024;
    int id = blockIdx.x;
    int j  = id >> 3;
    int qt2 = j >> 3;                      // [0,32)
    int half = qt2 >> 4;                   // KV half
    int qt = qt2 & 15;                     // [0,16)
    int g  = (id & 7) + ((j & 7) << 3);    // [0,64) (b,h) group; xcd = id&7
    int h  = g & 15;
    int b  = g >> 4;

    int tid  = threadIdx.x;
    int wave = tid >> 6, lane = tid & 63;
    int quad = lane >> 4, l16 = lane & 15;
    int q0 = qt * 64;

    // Q fragment (B-operand: n=q=l16, k=d=quad*8+j) straight from global
    const u16* qrow = qg + ((size_t)b * NQc + q0 + wave * 16 + l16) * HD + h * 64;
    bf16x8 aq0 = *(const bf16x8*)&qrow[quad * 8];
    bf16x8 aq1 = *(const bf16x8*)&qrow[32 + quad * 8];

    // staging source addressing (per lane): row lr in 8-row group, chunk swizzle
    int lr  = lane >> 3;                   // [0,8)
    int csw = (lane & 7) ^ lr;             // source 16B chunk for phys lane&7
    const u16* kbase = kg  + ((size_t)b * NKVc + wave * 8 + lr) * HD + h * 64 + csw * 8;
    const u16* vbase = vtg + (((size_t)b * 16 + h) * 64 + wave * 8 + lr) * (size_t)NKVc + csw * 8;
    u16* kl = Ks  + (wave * 8) * 64;
    u16* vl = Vst + (wave * 8) * 64;

    f32x4 O[4], lacc;
#pragma unroll
    for (int dt = 0; dt < 4; ++dt) O[dt] = (f32x4){0.f, 0.f, 0.f, 0.f};
    lacc = (f32x4){0.f, 0.f, 0.f, 0.f};

    bf16x4 ones4;
#pragma unroll
    for (int jj = 0; jj < 4; ++jj) ones4[jj] = (short)0x3F80;

    // bit-mask row: 64 u32 per q-row, bit index == kv index
    const u32* mrowb = mbits + ((size_t)b * NQc + q0 + wave * 16 + l16) * 64;

    int l7 = l16 & 7;
    int kvbeg = half << 10;

    for (int kv0 = kvbeg; kv0 < kvbeg + 1024; kv0 += 64) {
        __syncthreads();
#pragma unroll
        for (int i = 0; i < 2; ++i) {
            // K rows kv0+i*32+wave*8+lr ; V (d-rows) i*32+wave*8+lr, cols kv0
            async16(kl + i * 32 * 64, kbase + ((size_t)kv0 + i * 32) * HD);
            async16(vl + i * 32 * 64, vbase + (size_t)(i * 32) * NKVc + kv0);
        }
        __syncthreads();

        uint2 bw = *(const uint2*)&mrowb[kv0 >> 5];   // bits kv0..kv0+63

        // per nt: S^T tile -> exp2 -> mask -> bf16x4 P^T fragment
        bf16x4 pfr[4];
#pragma unroll
        for (int nt = 0; nt < 4; ++nt) {
            const u16* krow = Ks + (nt * 16 + l16) * 64;
            bf16x8 bk0 = *(const bf16x8*)&krow[(quad ^ l7) * 8];
            bf16x8 bk1 = *(const bf16x8*)&krow[((4 + quad) ^ l7) * 8];
            f32x4 st = (f32x4){0.f, 0.f, 0.f, 0.f};
            st = __builtin_amdgcn_mfma_f32_16x16x32_bf16(bk0, aq0, st, 0, 0, 0);
            st = __builtin_amdgcn_mfma_f32_16x16x32_bf16(bk1, aq1, st, 0, 0, 0);

            u32 w  = (nt < 2) ? bw.x : bw.y;
            u32 m4 = (w >> (((nt & 1) << 4) + (quad << 2))) & 0xFu;
            u32 m01 = ((m4 & 1u) ? 0xFFFFu : 0u) | ((m4 & 2u) ? 0xFFFF0000u : 0u);
            u32 m23 = ((m4 & 4u) ? 0xFFFFu : 0u) | ((m4 & 8u) ? 0xFFFF0000u : 0u);
            u32 p01 = pkbf(fexp2(st[0]), fexp2(st[1])) & m01;
            u32 p23 = pkbf(fexp2(st[2]), fexp2(st[3])) & m23;
            uint2 pu; pu.x = p01; pu.y = p23;
            pfr[nt] = *(const bf16x4*)&pu;

            lacc = __builtin_amdgcn_mfma_f32_16x16x16bf16_1k(ones4, pfr[nt], lacc, 0, 0, 0);
        }

        // O^T += V^T . P^T   (A-frag: d-row = dt*16+l16, kv = kvs*16+quad*4)
#pragma unroll
        for (int dt = 0; dt < 4; ++dt) {
            const u16* vrow = Vst + (dt * 16 + l16) * 64;
#pragma unroll
            for (int kvs = 0; kvs < 4; ++kvs) {
                int gran = ((kvs << 1) | (quad >> 1)) ^ l7;   // 16B granule (2 per read-half)
                bf16x4 av = *(const bf16x4*)&vrow[gran * 8 + (quad & 1) * 4];
                O[dt] = __builtin_amdgcn_mfma_f32_16x16x16bf16_1k(av, pfr[kvs], O[dt], 0, 0, 0);
            }
        }
    }

    // epilogue: un-normalized f32 partials, per-batch [q][hd] layout
    int qi = q0 + wave * 16 + l16;
    float* ob;
    if (half) ob = (b == 0) ? o1b0 : (b == 1) ? o1b1 : (b == 2) ? o1b2 : o1b3;
    else      ob = (b == 0) ? o0b0 : (b == 1) ? o0b1 : (b == 2) ? o0b2 : o0b3;
    float* orow = ob + (size_t)qi * 1024 + h * 64;
#pragma unroll
    for (int dt = 0; dt < 4; ++dt)
        *(float4*)&orow[dt * 16 + quad * 4] = (float4){O[dt][0], O[dt][1], O[dt][2], O[dt][3]};

    float* lp = half ? lacc1 : lacc0;
    if (quad == 0) lp[((size_t)b * 16 + h) * 1024 + qi] = lacc[0];
}

// ------------------------------------------------------------- combine halves
__global__ __launch_bounds__(256) void combine_halves(const float* __restrict__ o0b0,
                                                      const float* __restrict__ o0b1,
                                                      const float* __restrict__ o0b2,
                                                      const float* __restrict__ o0b3,
                                                      const float* __restrict__ o1b0,
                                                      const float* __restrict__ o1b1,
                                                      const float* __restrict__ o1b2,
                                                      const float* __restrict__ o1b3,
                                                      const float* __restrict__ l0,
                                                      const float* __restrict__ l1,
                                                      u16* __restrict__ ao) {
    int row = blockIdx.x;                 // b*1024 + q
    int b = row >> 10, qq = row & 1023;
    const float* p0 = (b == 0) ? o0b0 : (b == 1) ? o0b1 : (b == 2) ? o0b2 : o0b3;
    const float* p1 = (b == 0) ? o1b0 : (b == 1) ? o1b1 : (b == 2) ? o1b2 : o1b3;
    int tid = threadIdx.x;
    int hd = tid * 4;
    int h  = hd >> 6;
    float4 a = *(const float4*)&p0[(size_t)qq * 1024 + hd];
    float4 c = *(const float4*)&p1[(size_t)qq * 1024 + hd];
    size_t li = ((size_t)b * 16 + h) * 1024 + qq;
    float inv = 1.0f / (l0[li] + l1[li]);
    uint2 o;
    o.x = pkbf((a.x + c.x) * inv, (a.y + c.y) * inv);
    o.y = pkbf((a.z + c.z) * inv, (a.w + c.w) * inv);
    *(uint2*)&ao[(size_t)row * 1024 + hd] = o;
}

// ---------------------------------------------------------------- launch
extern "C" void kernel_launch(void* const* d_in, const int* in_sizes, int n_in,
                              void* d_out, int out_size, void* d_ws, size_t ws_size,
                              hipStream_t stream) {
    const void* x     = d_in[0];
    const void* key   = d_in[1];
    const void* value = d_in[2];
    const int*  mask  = (const int*)d_in[3];
    const void* Wq    = d_in[4];
    const void* Wk    = d_in[5];
    const void* Wv    = d_in[6];
    const void* Wo    = d_in[7];
    const void* gamma = d_in[8];
    const void* beta  = d_in[9];

    // ws layout (65 MB), time-multiplexed (all concurrent uses disjoint):
    //  @0   flag
    //  @1   xn [8MB] (prep out; mid-Q in)   -> after mid: o0b0@1..5, o0b1@5..9
    //  @9   mbits@9..10 (mid-mask out), o0b2@10..14, o0b3@14..18, o1b0@18..22,
    //       la@22..22.5
    //  @25  q@25..33 (mid-Q out), o1b2@33..37, o1b3@37..41
    //  @41  vT [16MB] (mid-VK out; attn in) -> after attn: ao@41..49
    //  @57  Wqt@57 (mid-Q in), Wkt@59, Wvt@61 (mid-VK in), Wot@63 (ogemm in);
    //       o1b1@59..63 written only by attn (Wkt/Wvt dead by then)
    //  k (16MB bf16) lives in d_out until the final gemm overwrites it.
    //  mid-VK reads key/value INPUTS directly (conversion fused into A-staging).
    char* ws = (char*)d_ws;
    int* flag   = (int*)(ws);
    u16* xn     = (u16*)(ws + ( 1ull << 20));
    float* o0b0 = (float*)(ws + ( 1ull << 20));
    float* o0b1 = (float*)(ws + ( 5ull << 20));
    u32* mbits  = (u32*)(ws + ( 9ull << 20));
    float* o0b2 = (float*)(ws + (10ull << 20));
    float* o0b3 = (float*)(ws + (14ull << 20));
    float* o1b0 = (float*)(ws + (18ull << 20));
    float* la0  = (float*)(ws + (22ull << 20));
    float* la1  = (float*)(ws + (22ull << 20) + (256ull << 10));
    u16* q      = (u16*)(ws + (25ull << 20));
    float* o1b2 = (float*)(ws + (33ull << 20));
    float* o1b3 = (float*)(ws + (37ull << 20));
    u16* vT     = (u16*)(ws + (41ull << 20));
    u16* ao     = (u16*)(ws + (41ull << 20));
    u16* Wqt    = (u16*)(ws + (57ull << 20));
    u16* Wkt    = (u16*)(ws + (59ull << 20));
    float* o1b1 = (float*)(ws + (59ull << 20));
    u16* Wvt    = (u16*)(ws + (61ull << 20));
    u16* Wot    = (u16*)(ws + (63ull << 20));
    u16* k      = (u16*)d_out;

    const float QSCALE = 0.125f * 1.44269504f;   // d^-0.5 * log2(e) for exp2 softmax

    // prep: detect + LN + weight transpose, one dispatch
    prep_kernel<<<5121, 256, 0, stream>>>((const u32*)x, x,
                                          gamma, beta, Wq, Wk, Wv, Wo,
                                          xn, Wqt, Wkt, Wvt, Wot, flag);

    // mid: VK-gemm (first: critical path) + Q-gemm + mask pack, one dispatch
    mid_kernel<<<2560, 256, 0, stream>>>(value, Wvt, vT, key, Wkt, k,
                                         xn, Wqt, q, QSCALE,
                                         mask, (u64*)mbits, flag);

    attn_kernel<<<2048, 256, 0, stream>>>(q, k, vT, mbits,
                                          o0b0, o0b1, o0b2, o0b3,
                                          o1b0, o1b1, o1b2, o1b3, la0, la1);

    combine_halves<<<4096, 256, 0, stream>>>(o0b0, o0b1, o0b2, o0b3,
                                             o1b0, o1b1, o1b2, o1b3,
                                             la0, la1, ao);

    // O-gemm (64-tile, 512 blocks)
    ogemm64<<<512, 256, 0, stream>>>(ao, Wot, d_out, flag);
}

// Round 15
// 320.596 us; speedup vs baseline: 1.1139x; 1.1139x over previous
//
#include <hip/hip_runtime.h>

typedef unsigned short u16;
typedef unsigned int u32;
typedef unsigned char u8;
typedef unsigned long long u64;

typedef __attribute__((ext_vector_type(8))) short bf16x8;
typedef __attribute__((ext_vector_type(4))) short bf16x4;
typedef __attribute__((ext_vector_type(4))) float f32x4;

__device__ __forceinline__ float bf2f(u16 u) {
    union { u32 i; float f; } v; v.i = ((u32)u) << 16; return v.f;
}
__device__ __forceinline__ u16 f2bf(float f) {
    union { float f; u32 i; } v; v.f = f;
    u32 r = v.i + 0x7fffu + ((v.i >> 16) & 1u);
    return (u16)(r >> 16);
}
// pack two f32 -> bf16x2 in one u32 (low = a, high = b). Software RNE,
// bit-identical to f2bf pair, packed with ONE v_perm_b32.
// (HW v_cvt_pk_bf16_f32 retired: rounds/packs differently -> r1/r8 failures.)
__device__ __forceinline__ u32 pkbf(float a, float b) {
    union { float f; u32 i; } va, vb;
    va.f = a; vb.f = b;
    u32 ra = va.i + 0x7fffu + ((va.i >> 16) & 1u);
    u32 rb = vb.i + 0x7fffu + ((vb.i >> 16) & 1u);
    return __builtin_amdgcn_perm(rb, ra, 0x07060302u);
}
// raw v_exp_f32 (2^x). <=2 ULP vs OCML exp2f — negligible for softmax P.
__device__ __forceinline__ float fexp2(float x) { return __builtin_amdgcn_exp2f(x); }

// async global->LDS, 16B per lane; lds must be wave-uniform (lane*16 added by HW)
__device__ __forceinline__ void async16(u16* lds, const u16* g) {
    __builtin_amdgcn_global_load_lds(
        (const __attribute__((address_space(1))) void*)g,
        (__attribute__((address_space(3))) void*)lds, 16, 0, 0);
}

// =============================================================== PREP
// One dispatch: [0..4096) LayerNorm rows, [4096..5120) weight transpose,
// block 5120 writes flag. (K/V f32->bf16 conversion fused into VK A-staging.)
// Every block self-detects dtype on x's first 4KB (identical words+threshold
// as the old detect_dtype kernel -> bit-identical decision; L2-broadcast).
__global__ __launch_bounds__(256) void prep_kernel(
        const u32* __restrict__ xw,          // x as words (for detect)
        const void* __restrict__ x_,
        const void* __restrict__ g_,
        const void* __restrict__ b_,
        const void* __restrict__ Wq, const void* __restrict__ Wk,
        const void* __restrict__ Wv, const void* __restrict__ Wo,
        u16* __restrict__ xn,
        u16* __restrict__ Wqt, u16* __restrict__ Wkt,
        u16* __restrict__ Wvt, u16* __restrict__ Wot,
        int* __restrict__ flagp) {
    __shared__ int  redi[4];
    __shared__ float redf[8];
    __shared__ u16 tsh[64][65];

    int tid = threadIdx.x;
    int wave = tid >> 6, lane = tid & 63;

    // --- self-detect on x[0..1023] words (matches old detect_dtype exactly)
    int hits = 0;
    for (int i = 0; i < 4; ++i) {
        u32 w = xw[tid * 4 + i];
        u32 e = (w >> 7) & 0xFFu;
        hits += (e >= 110u && e <= 131u) ? 1 : 0;
    }
    for (int off = 1; off < 64; off <<= 1) hits += __shfl_xor(hits, off, 64);
    if (lane == 0) redi[wave] = hits;
    __syncthreads();
    int flag = (redi[0] + redi[1] + redi[2] + redi[3] > 512) ? 1 : 0;

    int blk = blockIdx.x;

    if (blk == 5120) {                        // flag writer for later gemms
        if (tid == 0) flagp[0] = flag;
        return;
    }

    if (blk < 4096) {
        // ---------------- LayerNorm row
        int row = blk;
        float v[4];
        if (flag) {
            const u16* xr = (const u16*)x_ + (size_t)row * 1024;
            uint2 d = *(const uint2*)&xr[tid * 4];
            v[0] = bf2f((u16)(d.x & 0xffff));
            v[1] = bf2f((u16)(d.x >> 16));
            v[2] = bf2f((u16)(d.y & 0xffff));
            v[3] = bf2f((u16)(d.y >> 16));
        } else {
            const float* xr = (const float*)x_ + (size_t)row * 1024;
            float4 d = *(const float4*)&xr[tid * 4];
            v[0] = d.x; v[1] = d.y; v[2] = d.z; v[3] = d.w;
        }
        float s  = v[0] + v[1] + v[2] + v[3];
        float ss = v[0]*v[0] + v[1]*v[1] + v[2]*v[2] + v[3]*v[3];
        for (int off = 1; off < 64; off <<= 1) {
            s  += __shfl_xor(s,  off, 64);
            ss += __shfl_xor(ss, off, 64);
        }
        if (lane == 0) { redf[wave] = s; redf[4 + wave] = ss; }
        __syncthreads();
        s  = redf[0] + redf[1] + redf[2] + redf[3];
        ss = redf[4] + redf[5] + redf[6] + redf[7];
        float mu   = s * (1.0f / 1024.0f);
        float var  = ss * (1.0f / 1024.0f) - mu * mu;
        float rstd = rsqrtf(var + 1e-5f);
        float r[4];
        for (int j = 0; j < 4; ++j) {
            float g, bb;
            if (flag) { g = bf2f(((const u16*)g_)[tid * 4 + j]); bb = bf2f(((const u16*)b_)[tid * 4 + j]); }
            else      { g = ((const float*)g_)[tid * 4 + j];     bb = ((const float*)b_)[tid * 4 + j]; }
            r[j] = (v[j] - mu) * rstd * g + bb;
        }
        uint2 o;
        o.x = pkbf(r[0], r[1]);
        o.y = pkbf(r[2], r[3]);
        *(uint2*)&xn[(size_t)row * 1024 + tid * 4] = o;
    } else {
        // ---------------- weight transpose (64x64 tile)
        int t = blk - 4096;
        int w = t >> 8;                       // which weight
        int tt = t & 255;
        const void* src_ = (w == 0) ? Wq : (w == 1) ? Wk : (w == 2) ? Wv : Wo;
        u16* dst = (w == 0) ? Wqt : (w == 1) ? Wkt : (w == 2) ? Wvt : Wot;
        int bx = (tt & 15) * 64;
        int by = (tt >> 4) * 64;
        const int rows = 1024, cols = 1024;
        for (int i = 0; i < 16; ++i) {
            int r = i * 4 + (tid >> 6);
            int c = tid & 63;
            size_t idx = (size_t)(by + r) * cols + bx + c;
            tsh[r][c] = flag ? ((const u16*)src_)[idx] : f2bf(((const float*)src_)[idx]);
        }
        __syncthreads();
        for (int i = 0; i < 16; ++i) {
            int r = i * 4 + (tid >> 6);
            int c = tid & 63;
            dst[(size_t)(bx + r) * rows + by + c] = tsh[c][r];
        }
    }
}

// ================================= GEMM 64x128 tile body (M=4096 shapes)
__device__ __forceinline__ void gemm64_body(u16* As, u16* Bs,
                                            const u16* __restrict__ A,
                                            const u16* __restrict__ Bt,
                                            void* __restrict__ C_,
                                            int flag, int c_flagged, float cscale,
                                            int lid) {
    const int N = 1024, K = 1024, mdiv = 8;   // M = 4096 -> 64 m-tiles
    bool c_bf16 = c_flagged ? (flag != 0) : true;

    int j   = lid >> 3;
    int gy  = (lid & 7) + 8 * (j % mdiv);
    int bnt = j / mdiv;

    int tid  = threadIdx.x;
    int wave = tid >> 6, lane = tid & 63;
    int quad = lane >> 4, l16 = lane & 15;
    size_t bm = (size_t)gy * 64;
    size_t bn = (size_t)bnt * 128;
    int wm = (wave >> 1) * 32, wn = (wave & 1) * 64;

    int lr  = lane >> 3;
    int csw = (lane & 7) ^ lr;
    const u16* Ag = A  + (bm + wave * 8 + lr) * (size_t)K + csw * 8;
    const u16* Bg = Bt + (bn + wave * 8 + lr) * (size_t)K + csw * 8;
    u16* Al = &As[(wave * 8) * 64];
    u16* Bl = &Bs[(wave * 8) * 64];

    f32x4 acc[2][4];
#pragma unroll
    for (int i = 0; i < 2; ++i)
#pragma unroll
        for (int jj = 0; jj < 4; ++jj)
            acc[i][jj] = (f32x4){0.f, 0.f, 0.f, 0.f};

    int rsw = l16 & 7;

    for (int k0 = 0; k0 < K; k0 += 64) {
        __syncthreads();
#pragma unroll
        for (int i = 0; i < 2; ++i)
            async16(Al + i * 32 * 64, Ag + (size_t)i * 32 * K + k0);
#pragma unroll
        for (int i = 0; i < 4; ++i)
            async16(Bl + i * 32 * 64, Bg + (size_t)i * 32 * K + k0);
        __syncthreads();

#pragma unroll
        for (int ks = 0; ks < 2; ++ks) {
            int chunk = ((ks << 2) | quad) ^ rsw;
            bf16x8 af[2], bfr[4];
#pragma unroll
            for (int mi = 0; mi < 2; ++mi)
                af[mi]  = *(const bf16x8*)&As[(wm + mi * 16 + l16) * 64 + chunk * 8];
#pragma unroll
            for (int ni = 0; ni < 4; ++ni)
                bfr[ni] = *(const bf16x8*)&Bs[(wn + ni * 16 + l16) * 64 + chunk * 8];
#pragma unroll
            for (int mi = 0; mi < 2; ++mi)
#pragma unroll
                for (int ni = 0; ni < 4; ++ni)
                    acc[mi][ni] = __builtin_amdgcn_mfma_f32_16x16x32_bf16(
                        af[mi], bfr[ni], acc[mi][ni], 0, 0, 0);
        }
    }

#pragma unroll
    for (int mi = 0; mi < 2; ++mi)
#pragma unroll
        for (int ni = 0; ni < 4; ++ni)
#pragma unroll
            for (int r = 0; r < 4; ++r) {
                size_t row = bm + wm + mi * 16 + quad * 4 + r;
                size_t col = bn + wn + ni * 16 + l16;
                float val = acc[mi][ni][r] * cscale;
                if (c_bf16) ((u16*)C_)[row * N + col]   = f2bf(val);
                else        ((float*)C_)[row * N + col] = val;
            }
}

// ========================= MID: V-GEMM + K-GEMM + Q-GEMM + mask_bits merged
// Round 14: launch_bounds back to (256,3) — the (256,5) clamp forced VGPR
// 76->48 and spilled acc (WRITE_SIZE +9MB, mid 93->126us). KEEP the VK-first
// segment order (register-neutral; critical-path blocks start immediately).
// [0..1024): VK gemm (seg 0=V, 1=K, fused f32->bf16 A-staging).
// [1024..1536): Q-gemm (64-tile).  [1536..2560): mask -> bit pack.
__global__ __launch_bounds__(256, 3) void mid_kernel(
        const void* __restrict__ A0, const u16* __restrict__ Bt0, u16* __restrict__ C0,
        const void* __restrict__ A1, const u16* __restrict__ Bt1, u16* __restrict__ C1,
        const u16* __restrict__ Aq, const u16* __restrict__ Btq, u16* __restrict__ Cq,
        float cscale,
        const int* __restrict__ m, u64* __restrict__ mb,
        const int* __restrict__ flagp) {
    __shared__ u16 sh[2 * 128 * 64];
    int blk = blockIdx.x;
    int tid = threadIdx.x;

    if (blk >= 1024 && blk < 1536) {
        // ---------------- Q projection gemm (xn x Wqt -> q, scaled)
        gemm64_body(sh, &sh[64 * 64], Aq, Btq, (void*)Cq, 1, 0, cscale, blk - 1024);
        return;
    }
    if (blk >= 1536) {
        // ---------------- mask bits (bit kv == __ballot lane)
        int mblk = blk - 1536;
        int wid  = (mblk * 256 + tid) >> 6;
        int lane = tid & 63;
        size_t base = (size_t)wid * 2048;
        for (int it = 0; it < 8; ++it) {
            u64 b0 = __ballot(m[base + it * 256 +   0 + lane] == 0);
            u64 b1 = __ballot(m[base + it * 256 +  64 + lane] == 0);
            u64 b2 = __ballot(m[base + it * 256 + 128 + lane] == 0);
            u64 b3 = __ballot(m[base + it * 256 + 192 + lane] == 0);
            if (lane == 0) {
                size_t idx = (base + it * 256) >> 6;
                mb[idx + 0] = b0; mb[idx + 1] = b1; mb[idx + 2] = b2; mb[idx + 3] = b3;
            }
        }
        return;
    }

    // ---------------- VK gemm (128-tile), fused f32->bf16 A-staging
    u16* As = sh;
    u16* Bs = &sh[128 * 64];
    const int N = 1024, K = 1024, mdiv = 8;
    int flag = *flagp;

    int id  = blk;
    int seg = id >> 9;                 // 0 = V, 1 = K
    int lid = id & 511;
    const void* A  = seg ? A1 : A0;
    const u16* Bt = seg ? Bt1 : Bt0;

    int j   = lid >> 3;
    int gy  = (lid & 7) + 8 * (j % mdiv);
    int bnt = j / mdiv;

    int wave = tid >> 6, lane = tid & 63;
    int quad = lane >> 4, l16 = lane & 15;
    size_t bm = (size_t)gy * 128;
    size_t bn = (size_t)bnt * 128;
    int wm = (wave >> 1) * 64, wn = (wave & 1) * 64;

    int lr  = lane >> 3;
    int csw = (lane & 7) ^ lr;
    size_t arow = bm + wave * 32 + lr;
    int    acol = csw * 8;
    const u16* Bg = Bt + (bn + wave * 32 + lr) * (size_t)K + acol;
    u16* Al = &As[(wave * 32) * 64];
    u16* Bl = &Bs[(wave * 32) * 64];

    f32x4 acc[4][4];
#pragma unroll
    for (int i = 0; i < 4; ++i)
#pragma unroll
        for (int jj = 0; jj < 4; ++jj)
            acc[i][jj] = (f32x4){0.f, 0.f, 0.f, 0.f};

    int rsw = l16 & 7;

    for (int k0 = 0; k0 < K; k0 += 64) {
        __syncthreads();
        // B: async global->LDS (proven path)
#pragma unroll
        for (int i = 0; i < 4; ++i)
            async16(Bl + i * 8 * 64, Bg + (size_t)i * 8 * K + k0);
        // A: reg-staged with fused dtype conversion; identical LDS layout
        if (flag) {
#pragma unroll
            for (int i = 0; i < 4; ++i) {
                size_t gidx = (arow + i * 8) * (size_t)K + k0 + acol;
                uint4 v = *(const uint4*)&((const u16*)A)[gidx];
                *(uint4*)&Al[i * 8 * 64 + lane * 8] = v;
            }
        } else {
#pragma unroll
            for (int i = 0; i < 4; ++i) {
                size_t gidx = (arow + i * 8) * (size_t)K + k0 + acol;
                float4 f0 = *(const float4*)&((const float*)A)[gidx];
                float4 f1 = *(const float4*)&((const float*)A)[gidx + 4];
                uint4 v;
                v.x = pkbf(f0.x, f0.y);
                v.y = pkbf(f0.z, f0.w);
                v.z = pkbf(f1.x, f1.y);
                v.w = pkbf(f1.z, f1.w);
                *(uint4*)&Al[i * 8 * 64 + lane * 8] = v;
            }
        }
        __syncthreads();

#pragma unroll
        for (int ks = 0; ks < 2; ++ks) {
            int chunk = ((ks << 2) | quad) ^ rsw;
            bf16x8 af[4], bfr[4];
#pragma unroll
            for (int mi = 0; mi < 4; ++mi)
                af[mi]  = *(const bf16x8*)&As[(wm + mi * 16 + l16) * 64 + chunk * 8];
#pragma unroll
            for (int ni = 0; ni < 4; ++ni)
                bfr[ni] = *(const bf16x8*)&Bs[(wn + ni * 16 + l16) * 64 + chunk * 8];
#pragma unroll
            for (int mi = 0; mi < 4; ++mi)
#pragma unroll
                for (int ni = 0; ni < 4; ++ni)
                    acc[mi][ni] = __builtin_amdgcn_mfma_f32_16x16x32_bf16(
                        af[mi], bfr[ni], acc[mi][ni], 0, 0, 0);
        }
    }

    if (!seg) {
        // V: transposed per-head layout [b][h][d][kv].
        // Stage acc into sh as [n=hd][m=kv] bf16 (XOR-swizzled 16B chunks),
        // then write rows back coalesced (256B segments).
        __syncthreads();
#pragma unroll
        for (int ni = 0; ni < 4; ++ni) {
            int n  = wn + ni * 16 + l16;
            int s7 = n & 7;
#pragma unroll
            for (int mi = 0; mi < 4; ++mi) {
                int mm = wm + mi * 16 + quad * 4;
                int base = n * 128 + ((((mm >> 3) ^ s7) << 3) | (mm & 7));
                *(u32*)&sh[base]     = pkbf(acc[mi][ni][0], acc[mi][ni][1]);
                *(u32*)&sh[base + 2] = pkbf(acc[mi][ni][2], acc[mi][ni][3]);
            }
        }
        __syncthreads();
        int trow = tid >> 4;
        int tch  = tid & 15;
        size_t bb = bm >> 11;
        size_t kvb = (bm & 2047) + tch * 8;
        u16* C = C0;
#pragma unroll
        for (int it = 0; it < 8; ++it) {
            int n = it * 16 + trow;
            uint4 v = *(const uint4*)&sh[n * 128 + ((tch ^ (n & 7)) << 3)];
            size_t ng = bn + n;
            size_t hh = ng >> 6, d = ng & 63;
            *(uint4*)&C[((bb * 16 + hh) * 64 + d) * 2048 + kvb] = v;
        }
    } else {
        u16* C = C1;
#pragma unroll
        for (int mi = 0; mi < 4; ++mi)
#pragma unroll
            for (int ni = 0; ni < 4; ++ni)
#pragma unroll
                for (int r = 0; r < 4; ++r) {
                    size_t row = bm + wm + mi * 16 + quad * 4 + r;
                    size_t col = bn + wn + ni * 16 + l16;
                    C[row * N + col] = f2bf(acc[mi][ni][r]);
                }
    }
}

// =============================================== O-GEMM (64-tile, flag out)
__global__ __launch_bounds__(256, 3) void ogemm64(const u16* __restrict__ A,
                                                  const u16* __restrict__ Bt,
                                                  void* __restrict__ C_,
                                                  const int* __restrict__ flagp) {
    __shared__ u16 As[64 * 64];
    __shared__ u16 Bs[128 * 64];
    int flag = *flagp;
    gemm64_body(As, Bs, A, Bt, C_, flag, 1, 1.0f, blockIdx.x);
}

// ---------------------------------------------------------------- Attention
// S^T formulation, XCD-grouped, async XOR-swizzled staging, 2-way KV-split.
// P-pack: software RNE pkbf (perm-packed, bit-exact). HW cvt_pk retired.
__global__ __launch_bounds__(256) void attn_kernel(const u16* __restrict__ qg,
                                                   const u16* __restrict__ kg,
                                                   const u16* __restrict__ vtg,
                                                   const u32* __restrict__ mbits,
                                                   float* __restrict__ o0b0,
                                                   float* __restrict__ o0b1,
                                                   float* __restrict__ o0b2,
                                                   float* __restrict__ o0b3,
                                                   float* __restrict__ o1b0,
                                                   float* __restrict__ o1b1,
                                                   float* __restrict__ o1b2,
                                                   float* __restrict__ o1b3,
                                                   float* __restrict__ lacc0,
                                                   float* __restrict__ lacc1) {
    __shared__ u16 Ks[64 * 64];
    __shared__ u16 Vst[64 * 64];     // [d][kv], swizzled

    const int NQc = 1024, NKVc = 2048, HD = 1024;
    int id = blockIdx.x;
    int j  = id >> 3;
    int qt2 = j >> 3;                      // [0,32)
    int half = qt2 >> 4;                   // KV half
    int qt = qt2 & 15;                     // [0,16)
    int g  = (id & 7) + ((j & 7) << 3);    // [0,64) (b,h) group; xcd = id&7
    int h  = g & 15;
    int b  = g >> 4;

    int tid  = threadIdx.x;
    int wave = tid >> 6, lane = tid & 63;
    int quad = lane >> 4, l16 = lane & 15;
    int q0 = qt * 64;

    // Q fragment (B-operand: n=q=l16, k=d=quad*8+j) straight from global
    const u16* qrow = qg + ((size_t)b * NQc + q0 + wave * 16 + l16) * HD + h * 64;
    bf16x8 aq0 = *(const bf16x8*)&qrow[quad * 8];
    bf16x8 aq1 = *(const bf16x8*)&qrow[32 + quad * 8];

    // staging source addressing (per lane): row lr in 8-row group, chunk swizzle
    int lr  = lane >> 3;                   // [0,8)
    int csw = (lane & 7) ^ lr;             // source 16B chunk for phys lane&7
    const u16* kbase = kg  + ((size_t)b * NKVc + wave * 8 + lr) * HD + h * 64 + csw * 8;
    const u16* vbase = vtg + (((size_t)b * 16 + h) * 64 + wave * 8 + lr) * (size_t)NKVc + csw * 8;
    u16* kl = Ks  + (wave * 8) * 64;
    u16* vl = Vst + (wave * 8) * 64;

    f32x4 O[4], lacc;
#pragma unroll
    for (int dt = 0; dt < 4; ++dt) O[dt] = (f32x4){0.f, 0.f, 0.f, 0.f};
    lacc = (f32x4){0.f, 0.f, 0.f, 0.f};

    bf16x4 ones4;
#pragma unroll
    for (int jj = 0; jj < 4; ++jj) ones4[jj] = (short)0x3F80;

    // bit-mask row: 64 u32 per q-row, bit index == kv index
    const u32* mrowb = mbits + ((size_t)b * NQc + q0 + wave * 16 + l16) * 64;

    int l7 = l16 & 7;
    int kvbeg = half << 10;

    for (int kv0 = kvbeg; kv0 < kvbeg + 1024; kv0 += 64) {
        __syncthreads();
#pragma unroll
        for (int i = 0; i < 2; ++i) {
            // K rows kv0+i*32+wave*8+lr ; V (d-rows) i*32+wave*8+lr, cols kv0
            async16(kl + i * 32 * 64, kbase + ((size_t)kv0 + i * 32) * HD);
            async16(vl + i * 32 * 64, vbase + (size_t)(i * 32) * NKVc + kv0);
        }
        __syncthreads();

        uint2 bw = *(const uint2*)&mrowb[kv0 >> 5];   // bits kv0..kv0+63

        // per nt: S^T tile -> exp2 -> mask -> bf16x4 P^T fragment
        bf16x4 pfr[4];
#pragma unroll
        for (int nt = 0; nt < 4; ++nt) {
            const u16* krow = Ks + (nt * 16 + l16) * 64;
            bf16x8 bk0 = *(const bf16x8*)&krow[(quad ^ l7) * 8];
            bf16x8 bk1 = *(const bf16x8*)&krow[((4 + quad) ^ l7) * 8];
            f32x4 st = (f32x4){0.f, 0.f, 0.f, 0.f};
            st = __builtin_amdgcn_mfma_f32_16x16x32_bf16(bk0, aq0, st, 0, 0, 0);
            st = __builtin_amdgcn_mfma_f32_16x16x32_bf16(bk1, aq1, st, 0, 0, 0);

            u32 w  = (nt < 2) ? bw.x : bw.y;
            u32 m4 = (w >> (((nt & 1) << 4) + (quad << 2))) & 0xFu;
            u32 m01 = ((m4 & 1u) ? 0xFFFFu : 0u) | ((m4 & 2u) ? 0xFFFF0000u : 0u);
            u32 m23 = ((m4 & 4u) ? 0xFFFFu : 0u) | ((m4 & 8u) ? 0xFFFF0000u : 0u);
            u32 p01 = pkbf(fexp2(st[0]), fexp2(st[1])) & m01;
            u32 p23 = pkbf(fexp2(st[2]), fexp2(st[3])) & m23;
            uint2 pu; pu.x = p01; pu.y = p23;
            pfr[nt] = *(const bf16x4*)&pu;

            lacc = __builtin_amdgcn_mfma_f32_16x16x16bf16_1k(ones4, pfr[nt], lacc, 0, 0, 0);
        }

        // O^T += V^T . P^T   (A-frag: d-row = dt*16+l16, kv = kvs*16+quad*4)
#pragma unroll
        for (int dt = 0; dt < 4; ++dt) {
            const u16* vrow = Vst + (dt * 16 + l16) * 64;
#pragma unroll
            for (int kvs = 0; kvs < 4; ++kvs) {
                int gran = ((kvs << 1) | (quad >> 1)) ^ l7;   // 16B granule (2 per read-half)
                bf16x4 av = *(const bf16x4*)&vrow[gran * 8 + (quad & 1) * 4];
                O[dt] = __builtin_amdgcn_mfma_f32_16x16x16bf16_1k(av, pfr[kvs], O[dt], 0, 0, 0);
            }
        }
    }

    // epilogue: un-normalized f32 partials, per-batch [q][hd] layout
    int qi = q0 + wave * 16 + l16;
    float* ob;
    if (half) ob = (b == 0) ? o1b0 : (b == 1) ? o1b1 : (b == 2) ? o1b2 : o1b3;
    else      ob = (b == 0) ? o0b0 : (b == 1) ? o0b1 : (b == 2) ? o0b2 : o0b3;
    float* orow = ob + (size_t)qi * 1024 + h * 64;
#pragma unroll
    for (int dt = 0; dt < 4; ++dt)
        *(float4*)&orow[dt * 16 + quad * 4] = (float4){O[dt][0], O[dt][1], O[dt][2], O[dt][3]};

    float* lp = half ? lacc1 : lacc0;
    if (quad == 0) lp[((size_t)b * 16 + h) * 1024 + qi] = lacc[0];
}

// ------------------------------------------------------------- combine halves
__global__ __launch_bounds__(256) void combine_halves(const float* __restrict__ o0b0,
                                                      const float* __restrict__ o0b1,
                                                      const float* __restrict__ o0b2,
                                                      const float* __restrict__ o0b3,
                                                      const float* __restrict__ o1b0,
                                                      const float* __restrict__ o1b1,
                                                      const float* __restrict__ o1b2,
                                                      const float* __restrict__ o1b3,
                                                      const float* __restrict__ l0,
                                                      const float* __restrict__ l1,
                                                      u16* __restrict__ ao) {
    int row = blockIdx.x;                 // b*1024 + q
    int b = row >> 10, qq = row & 1023;
    const float* p0 = (b == 0) ? o0b0 : (b == 1) ? o0b1 : (b == 2) ? o0b2 : o0b3;
    const float* p1 = (b == 0) ? o1b0 : (b == 1) ? o1b1 : (b == 2) ? o1b2 : o1b3;
    int tid = threadIdx.x;
    int hd = tid * 4;
    int h  = hd >> 6;
    float4 a = *(const float4*)&p0[(size_t)qq * 1024 + hd];
    float4 c = *(const float4*)&p1[(size_t)qq * 1024 + hd];
    size_t li = ((size_t)b * 16 + h) * 1024 + qq;
    float inv = 1.0f / (l0[li] + l1[li]);
    uint2 o;
    o.x = pkbf((a.x + c.x) * inv, (a.y + c.y) * inv);
    o.y = pkbf((a.z + c.z) * inv, (a.w + c.w) * inv);
    *(uint2*)&ao[(size_t)row * 1024 + hd] = o;
}

// ---------------------------------------------------------------- launch
extern "C" void kernel_launch(void* const* d_in, const int* in_sizes, int n_in,
                              void* d_out, int out_size, void* d_ws, size_t ws_size,
                              hipStream_t stream) {
    const void* x     = d_in[0];
    const void* key   = d_in[1];
    const void* value = d_in[2];
    const int*  mask  = (const int*)d_in[3];
    const void* Wq    = d_in[4];
    const void* Wk    = d_in[5];
    const void* Wv    = d_in[6];
    const void* Wo    = d_in[7];
    const void* gamma = d_in[8];
    const void* beta  = d_in[9];

    // ws layout (65 MB), time-multiplexed (all concurrent uses disjoint):
    //  @0   flag
    //  @1   xn [8MB] (prep out; mid-Q in)   -> after mid: o0b0@1..5, o0b1@5..9
    //  @9   mbits@9..10 (mid-mask out), o0b2@10..14, o0b3@14..18, o1b0@18..22,
    //       la@22..22.5
    //  @25  q@25..33 (mid-Q out), o1b2@33..37, o1b3@37..41
    //  @41  vT [16MB] (mid-VK out; attn in) -> after attn: ao@41..49
    //  @57  Wqt@57 (mid-Q in), Wkt@59, Wvt@61 (mid-VK in), Wot@63 (ogemm in);
    //       o1b1@59..63 written only by attn (Wkt/Wvt dead by then)
    //  k (16MB bf16) lives in d_out until the final gemm overwrites it.
    //  mid-VK reads key/value INPUTS directly (conversion fused into A-staging).
    char* ws = (char*)d_ws;
    int* flag   = (int*)(ws);
    u16* xn     = (u16*)(ws + ( 1ull << 20));
    float* o0b0 = (float*)(ws + ( 1ull << 20));
    float* o0b1 = (float*)(ws + ( 5ull << 20));
    u32* mbits  = (u32*)(ws + ( 9ull << 20));
    float* o0b2 = (float*)(ws + (10ull << 20));
    float* o0b3 = (float*)(ws + (14ull << 20));
    float* o1b0 = (float*)(ws + (18ull << 20));
    float* la0  = (float*)(ws + (22ull << 20));
    float* la1  = (float*)(ws + (22ull << 20) + (256ull << 10));
    u16* q      = (u16*)(ws + (25ull << 20));
    float* o1b2 = (float*)(ws + (33ull << 20));
    float* o1b3 = (float*)(ws + (37ull << 20));
    u16* vT     = (u16*)(ws + (41ull << 20));
    u16* ao     = (u16*)(ws + (41ull << 20));
    u16* Wqt    = (u16*)(ws + (57ull << 20));
    u16* Wkt    = (u16*)(ws + (59ull << 20));
    float* o1b1 = (float*)(ws + (59ull << 20));
    u16* Wvt    = (u16*)(ws + (61ull << 20));
    u16* Wot    = (u16*)(ws + (63ull << 20));
    u16* k      = (u16*)d_out;

    const float QSCALE = 0.125f * 1.44269504f;   // d^-0.5 * log2(e) for exp2 softmax

    // prep: detect + LN + weight transpose, one dispatch
    prep_kernel<<<5121, 256, 0, stream>>>((const u32*)x, x,
                                          gamma, beta, Wq, Wk, Wv, Wo,
                                          xn, Wqt, Wkt, Wvt, Wot, flag);

    // mid: VK-gemm (first: critical path) + Q-gemm + mask pack, one dispatch
    mid_kernel<<<2560, 256, 0, stream>>>(value, Wvt, vT, key, Wkt, k,
                                         xn, Wqt, q, QSCALE,
                                         mask, (u64*)mbits, flag);

    attn_kernel<<<2048, 256, 0, stream>>>(q, k, vT, mbits,
                                          o0b0, o0b1, o0b2, o0b3,
                                          o1b0, o1b1, o1b2, o1b3, la0, la1);

    combine_halves<<<4096, 256, 0, stream>>>(o0b0, o0b1, o0b2, o0b3,
                                             o1b0, o1b1, o1b2, o1b3,
                                             la0, la1, ao);

    // O-gemm (64-tile, 512 blocks)
    ogemm64<<<512, 256, 0, stream>>>(ao, Wot, d_out, flag);
}